// Round 12
// baseline (246.011 us; speedup 1.0000x reference)
//
#include <hip/hip_runtime.h>
#include <hip/hip_bf16.h>
#include <stdint.h>
#include <math.h>

#define B_ 4
#define T_ 2048
#define E_ 1024
#define H_ 16
#define D_ 64

typedef __attribute__((ext_vector_type(8))) short short8;
typedef __attribute__((ext_vector_type(4))) short short4v;
typedef __attribute__((ext_vector_type(4))) float f32x4;

#define MFMA_BF16(a, b, c) __builtin_amdgcn_mfma_f32_16x16x32_bf16((a), (b), (c), 0, 0, 0)

__device__ __forceinline__ unsigned short f2bf(float f) {
  union { float f; unsigned u; } v; v.f = f;
  unsigned r = v.u + 0x7FFFu + ((v.u >> 16) & 1u);  // RNE
  return (unsigned short)(r >> 16);
}

#define GLOAD_LDS16(g, l)                                                        \
  __builtin_amdgcn_global_load_lds((const __attribute__((address_space(1))) void*)(g), \
                                   (__attribute__((address_space(3))) void*)(l), 16, 0, 0)

// ---------------- fp32 -> bf16 convert (vectorized) ----------------
__global__ __launch_bounds__(256) void cvt_f32_bf16(const float* __restrict__ in,
                                                    unsigned short* __restrict__ out,
                                                    int n8) {
  int i = blockIdx.x * blockDim.x + threadIdx.x;
  if (i >= n8) return;
  const float4* p = (const float4*)(in + (size_t)i * 8);
  float4 a = p[0], b = p[1];
  short8 r;
  r[0] = (short)f2bf(a.x); r[1] = (short)f2bf(a.y);
  r[2] = (short)f2bf(a.z); r[3] = (short)f2bf(a.w);
  r[4] = (short)f2bf(b.x); r[5] = (short)f2bf(b.y);
  r[6] = (short)f2bf(b.z); r[7] = (short)f2bf(b.w);
  *(short8*)(out + (size_t)i * 8) = r;
}

// 4 weight matrices in one launch (dest regions contiguous in ws)
__global__ __launch_bounds__(256) void cvt_w4(const float* __restrict__ w0,
                                              const float* __restrict__ w1,
                                              const float* __restrict__ w2,
                                              const float* __restrict__ w3,
                                              unsigned short* __restrict__ out) {
  int i = blockIdx.x * blockDim.x + threadIdx.x;  // one per 8 elems
  int which = i >> 17;                            // WE/8 = 2^17
  int off = i & 131071;
  const float* src = (which == 0) ? w0 : (which == 1) ? w1 : (which == 2) ? w2 : w3;
  const float4* p = (const float4*)(src + (size_t)off * 8);
  float4 a = p[0], b = p[1];
  short8 r;
  r[0] = (short)f2bf(a.x); r[1] = (short)f2bf(a.y);
  r[2] = (short)f2bf(a.z); r[3] = (short)f2bf(a.w);
  r[4] = (short)f2bf(b.x); r[5] = (short)f2bf(b.y);
  r[6] = (short)f2bf(b.z); r[7] = (short)f2bf(b.w);
  *(short8*)(out + ((size_t)which << 20) + (size_t)off * 8) = r;
}

// ---------------- fused QKV GEMM: C = x * W^T for W in {Wq,Wk,Wv} -------------
// sel 0/1 (Q,K): bf16 [B*H][T][D]. sel 2 (V): bf16 TRANSPOSED [B*H][D][T] via
// packed 8B stores (4 consecutive t at fixed d).
__global__ __launch_bounds__(256) void gemm_qkv(const unsigned short* __restrict__ A,
                                                const unsigned short* __restrict__ Wq,
                                                const unsigned short* __restrict__ Wk,
                                                const unsigned short* __restrict__ Wv,
                                                unsigned short* __restrict__ Qo,
                                                unsigned short* __restrict__ Ko,
                                                unsigned short* __restrict__ Vo) {
  __shared__ __align__(16) unsigned short Ab[128 * 64];
  __shared__ __align__(16) unsigned short Bb[128 * 64];
  const int K = E_;
  const int tid = threadIdx.x;
  const int wid = tid >> 6;
  const int lr = tid & 15;
  const int lk = (tid >> 4) & 3;
  const int wr = wid >> 1, wc = wid & 1;
  const int m0 = blockIdx.x * 128;
  const int sel = blockIdx.y >> 3;
  const int n0 = (blockIdx.y & 7) * 128;
  const unsigned short* Bm = (sel == 0) ? Wq : (sel == 1) ? Wk : Wv;
  unsigned short* outp = (sel == 0) ? Qo : (sel == 1) ? Ko : Vo;

  f32x4 acc[4][4] = {};

  for (int k0 = 0; k0 < K; k0 += 64) {
    __syncthreads();
#pragma unroll
    for (int pass = 0; pass < 4; ++pass) {
      int chunk = pass * 256 + tid;
      int row = chunk >> 3, inner = chunk & 7;
      const unsigned short* ga = A + (size_t)(m0 + row) * K + k0 + inner * 8;
      const unsigned short* gb = Bm + (size_t)(n0 + row) * K + k0 + inner * 8;
      unsigned short* la = Ab + (size_t)(pass * 256 + wid * 64) * 8;
      unsigned short* lb = Bb + (size_t)(pass * 256 + wid * 64) * 8;
      GLOAD_LDS16(ga, la);
      GLOAD_LDS16(gb, lb);
    }
    __syncthreads();
#pragma unroll
    for (int kk = 0; kk < 2; ++kk) {
      short8 af[4], bf[4];
#pragma unroll
      for (int mi = 0; mi < 4; ++mi)
        af[mi] = *(const short8*)&Ab[(wr * 64 + mi * 16 + lr) * 64 + kk * 32 + lk * 8];
#pragma unroll
      for (int ni = 0; ni < 4; ++ni)
        bf[ni] = *(const short8*)&Bb[(wc * 64 + ni * 16 + lr) * 64 + kk * 32 + lk * 8];
#pragma unroll
      for (int mi = 0; mi < 4; ++mi)
#pragma unroll
        for (int ni = 0; ni < 4; ++ni)
          acc[mi][ni] = MFMA_BF16(af[mi], bf[ni], acc[mi][ni]);
    }
  }

#pragma unroll
  for (int mi = 0; mi < 4; ++mi)
#pragma unroll
    for (int ni = 0; ni < 4; ++ni) {
      int row0 = m0 + wr * 64 + mi * 16 + lk * 4;
      int col = n0 + wc * 64 + ni * 16 + lr;
      int b = row0 >> 11, t0 = row0 & (T_ - 1), h = col >> 6, d = col & (D_ - 1);
      if (sel == 2) {
        short4v vv;
#pragma unroll
        for (int r = 0; r < 4; ++r) vv[r] = (short)f2bf(acc[mi][ni][r]);
        *(short4v*)&outp[(((size_t)(b * H_ + h)) * D_ + d) * T_ + t0] = vv;  // [BH][D][T]
      } else {
#pragma unroll
        for (int r = 0; r < 4; ++r)
          outp[(((size_t)(b * H_ + h)) * T_ + t0 + r) * D_ + d] = f2bf(acc[mi][ni][r]);
      }
    }
}

// ---------------- out-proj GEMM: fp32 out + bias ----------------
__global__ __launch_bounds__(256) void gemm_out(const unsigned short* __restrict__ A,
                                                const unsigned short* __restrict__ Bm,
                                                float* __restrict__ outp,
                                                const float* __restrict__ bias,
                                                int M, int N, int K) {
  __shared__ __align__(16) unsigned short Ab[128 * 64];
  __shared__ __align__(16) unsigned short Bb[128 * 64];
  const int tid = threadIdx.x;
  const int wid = tid >> 6;
  const int lr = tid & 15;
  const int lk = (tid >> 4) & 3;
  const int wr = wid >> 1, wc = wid & 1;
  const int m0 = blockIdx.x * 128, n0 = blockIdx.y * 128;

  f32x4 acc[4][4] = {};

  for (int k0 = 0; k0 < K; k0 += 64) {
    __syncthreads();
#pragma unroll
    for (int pass = 0; pass < 4; ++pass) {
      int chunk = pass * 256 + tid;
      int row = chunk >> 3, inner = chunk & 7;
      const unsigned short* ga = A + (size_t)(m0 + row) * K + k0 + inner * 8;
      const unsigned short* gb = Bm + (size_t)(n0 + row) * K + k0 + inner * 8;
      unsigned short* la = Ab + (size_t)(pass * 256 + wid * 64) * 8;
      unsigned short* lb = Bb + (size_t)(pass * 256 + wid * 64) * 8;
      GLOAD_LDS16(ga, la);
      GLOAD_LDS16(gb, lb);
    }
    __syncthreads();
#pragma unroll
    for (int kk = 0; kk < 2; ++kk) {
      short8 af[4], bf[4];
#pragma unroll
      for (int mi = 0; mi < 4; ++mi)
        af[mi] = *(const short8*)&Ab[(wr * 64 + mi * 16 + lr) * 64 + kk * 32 + lk * 8];
#pragma unroll
      for (int ni = 0; ni < 4; ++ni)
        bf[ni] = *(const short8*)&Bb[(wc * 64 + ni * 16 + lr) * 64 + kk * 32 + lk * 8];
#pragma unroll
      for (int mi = 0; mi < 4; ++mi)
#pragma unroll
        for (int ni = 0; ni < 4; ++ni)
          acc[mi][ni] = MFMA_BF16(af[mi], bf[ni], acc[mi][ni]);
    }
  }

#pragma unroll
  for (int mi = 0; mi < 4; ++mi)
#pragma unroll
    for (int ni = 0; ni < 4; ++ni)
#pragma unroll
      for (int r = 0; r < 4; ++r) {
        int row = m0 + wr * 64 + mi * 16 + lk * 4 + r;
        int col = n0 + wc * 64 + ni * 16 + lr;
        outp[(size_t)row * N + col] = acc[mi][ni][r] + bias[col];
      }
}

// ---------------- fused causal flash attention ----------------
// 4096 blocks x 64 thr; one 32-row q-chunk per wave (fine units -> backlog).
// Lagged-PV pipeline (r11) with SINGLE-buffered K/V registers:
//   iter i: issue V(i-1) load -> QK(i) from kf -> issue K(i+1) into kf (dead)
//           -> mask/rowmax -> PV(i-1) from other P-buffer with v=V(i-1)
//           -> rescale -> pack(i).
// V latency covered by QK+rowmax; K latency covered by softmax+PV+pack.
// Lean body targets <=~200 VGPR -> ~10 waves/CU sustained (no launch cap:
// r8/r9 showed caps spill).
__global__ __launch_bounds__(64) void attn_fused(const unsigned short* __restrict__ Q,
                                                 const unsigned short* __restrict__ K,
                                                 const unsigned short* __restrict__ VT,
                                                 unsigned short* __restrict__ ctx) {
  __shared__ __align__(16) unsigned short Pl[2 * 32 * 72];  // 2 bufs x 32 rows x 144B
  const int lane = threadIdx.x & 63;
  const int lr = lane & 15;
  const int lk = lane >> 4;

  // XCD swizzle: 8 heads/XCD; heaviest chunks dispatched first.
  const int bid = blockIdx.x;
  const int xcd = bid & 7;
  const int p = bid >> 3;           // 0..511 per XCD
  const int chunk = 63 - (p >> 3);  // heavy first
  const int bh = xcd * 8 + (p & 7);
  const int q0 = chunk * 32;

  const unsigned short* Qh = Q + (size_t)bh * T_ * D_;
  const unsigned short* Kh = K + (size_t)bh * T_ * D_;
  const unsigned short* Vh = VT + (size_t)bh * T_ * D_;  // [D][T]
  char* Pbase = (char*)Pl;

  const float SC = 0.125f * 1.44269504089f;  // 1/sqrt(D) * log2(e)

  short8 vones;
#pragma unroll
  for (int j = 0; j < 8; ++j) vones[j] = (short)0x3F80;  // bf16 1.0

  // Q as B-operand: col=q=lr, k=d
  short8 qf[2][2];
#pragma unroll
  for (int a = 0; a < 2; ++a)
#pragma unroll
    for (int kb = 0; kb < 2; ++kb)
      qf[a][kb] = *(const short8*)&Qh[(size_t)(q0 + a * 16 + lr) * D_ + kb * 32 + lk * 8];

  f32x4 o[2][4] = {};
  f32x4 lsum[2] = {};
  float mrun[2] = {-1e30f, -1e30f};

  const int nt = (q0 >> 6) + 1;
  const int ql0 = q0 & 63;  // q-local base within diag tile

  short8 kf[2][4];  // single K buffer: holds K(i) at iter-i entry
  short8 v[2][4];   // single V buffer: holds V(i-1) during iter i

  // K(0)
#pragma unroll
  for (int kb = 0; kb < 2; ++kb)
#pragma unroll
    for (int n = 0; n < 4; ++n)
      kf[kb][n] = *(const short8*)&Kh[(size_t)(n * 16 + lr) * D_ + kb * 32 + lk * 8];

  for (int i = 0; i < nt; ++i) {
    // issue V(i-1) load (consumed by PV(i-1) below; latency under QK+rowmax)
    if (i > 0) {
      const unsigned short* Vtt = Vh + (size_t)(i - 1) * 64;
#pragma unroll
      for (int kb = 0; kb < 2; ++kb)
#pragma unroll
        for (int nd = 0; nd < 4; ++nd)
          v[kb][nd] = *(const short8*)&Vtt[(size_t)(nd * 16 + lr) * T_ + kb * 32 + lk * 8];
    }

    // S^T = K Q^T : row=kv (n*16+lk*4+r), col=q (lr)
    f32x4 st[2][4] = {};
#pragma unroll
    for (int kb = 0; kb < 2; ++kb)
#pragma unroll
      for (int a = 0; a < 2; ++a)
#pragma unroll
        for (int n = 0; n < 4; ++n)
          st[a][n] = MFMA_BF16(kf[kb][n], qf[a][kb], st[a][n]);

    // kf dead -> prefetch K(i+1) (latency covered by softmax+PV+pack)
    {
      int tn = (i + 1 < nt) ? i + 1 : i;
      const unsigned short* Kt = Kh + (size_t)tn * 64 * D_;
#pragma unroll
      for (int kb = 0; kb < 2; ++kb)
#pragma unroll
        for (int n = 0; n < 4; ++n)
          kf[kb][n] = *(const short8*)&Kt[(size_t)(n * 16 + lr) * D_ + kb * 32 + lk * 8];
    }

    if (i == nt - 1) {  // diagonal tile: mask kv_local > q_local
#pragma unroll
      for (int a = 0; a < 2; ++a)
#pragma unroll
        for (int n = 0; n < 4; ++n)
#pragma unroll
          for (int r = 0; r < 4; ++r)
            if (n * 16 + lk * 4 + r > ql0 + a * 16 + lr) st[a][n][r] = -3e38f;
    }

    // row max (in-lane tree + 2 shuffles)
    float pm[2];
#pragma unroll
    for (int a = 0; a < 2; ++a) {
      float m0 = fmaxf(fmaxf(st[a][0][0], st[a][1][0]), fmaxf(st[a][2][0], st[a][3][0]));
      float m1 = fmaxf(fmaxf(st[a][0][1], st[a][1][1]), fmaxf(st[a][2][1], st[a][3][1]));
      float m2 = fmaxf(fmaxf(st[a][0][2], st[a][1][2]), fmaxf(st[a][2][2], st[a][3][2]));
      float m3 = fmaxf(fmaxf(st[a][0][3], st[a][1][3]), fmaxf(st[a][2][3], st[a][3][3]));
      float mx = fmaxf(fmaxf(m0, m1), fmaxf(m2, m3));
      mx = fmaxf(mx, __shfl_xor(mx, 16));
      mx = fmaxf(mx, __shfl_xor(mx, 32));
      pm[a] = mx * SC;
    }
    float need = fmaxf(pm[0] - mrun[0], pm[1] - mrun[1]);

    // PV(i-1): reads OTHER P buffer (written a full tile ago) + v = V(i-1),
    // BEFORE rescale (contribution belongs to the old running max).
    if (i > 0) {
      char* bufp = Pbase + ((i & 1) ^ 1) * 4608;
#pragma unroll
      for (int kb = 0; kb < 2; ++kb) {
        short8 pf0 = *(const short8*)(bufp + (0 + lr) * 144 + kb * 64 + lk * 16);
        short8 pf1 = *(const short8*)(bufp + (16 + lr) * 144 + kb * 64 + lk * 16);
#pragma unroll
        for (int nd = 0; nd < 4; ++nd) {
          o[0][nd] = MFMA_BF16(pf0, v[kb][nd], o[0][nd]);
          o[1][nd] = MFMA_BF16(pf1, v[kb][nd], o[1][nd]);
        }
        lsum[0] = MFMA_BF16(pf0, vones, lsum[0]);
        lsum[1] = MFMA_BF16(pf1, vones, lsum[1]);
      }
    }

    if (__any(need > 8.f)) {  // defer-max rescale (rare)
#pragma unroll
      for (int a = 0; a < 2; ++a) {
        float mnew = fmaxf(mrun[a], pm[a]);
        float sc = exp2f(mrun[a] - mnew);
        mrun[a] = mnew;
#pragma unroll
        for (int r = 0; r < 4; ++r) {
          float sco = __shfl(sc, (lane & 48) | (lk * 4 + r));
          lsum[a][r] *= sco;
#pragma unroll
          for (int nd = 0; nd < 4; ++nd) o[a][nd][r] *= sco;
        }
      }
    }

    // pack(i) -> current P buffer
    {
      char* bufc = Pbase + (i & 1) * 4608;
#pragma unroll
      for (int a = 0; a < 2; ++a)
#pragma unroll
        for (int n = 0; n < 4; ++n) {
          float2 p01, p23;
          p01.x = exp2f(fmaf(st[a][n][0], SC, -mrun[a]));
          p01.y = exp2f(fmaf(st[a][n][1], SC, -mrun[a]));
          p23.x = exp2f(fmaf(st[a][n][2], SC, -mrun[a]));
          p23.y = exp2f(fmaf(st[a][n][3], SC, -mrun[a]));
          __hip_bfloat162 b01 = __float22bfloat162_rn(p01);
          __hip_bfloat162 b23 = __float22bfloat162_rn(p23);
          uint2 w;
          w.x = *(unsigned*)&b01;
          w.y = *(unsigned*)&b23;
          *(uint2*)(bufc + (a * 16 + lr) * 144 + n * 32 + lk * 8) = w;
        }
    }
  }

  // epilogue: PV of last tile
  {
    const unsigned short* Vtt = Vh + (size_t)(nt - 1) * 64;
#pragma unroll
    for (int kb = 0; kb < 2; ++kb)
#pragma unroll
      for (int nd = 0; nd < 4; ++nd)
        v[kb][nd] = *(const short8*)&Vtt[(size_t)(nd * 16 + lr) * T_ + kb * 32 + lk * 8];
    char* bufp = Pbase + ((nt - 1) & 1) * 4608;
#pragma unroll
    for (int kb = 0; kb < 2; ++kb) {
      short8 pf0 = *(const short8*)(bufp + (0 + lr) * 144 + kb * 64 + lk * 16);
      short8 pf1 = *(const short8*)(bufp + (16 + lr) * 144 + kb * 64 + lk * 16);
#pragma unroll
      for (int nd = 0; nd < 4; ++nd) {
        o[0][nd] = MFMA_BF16(pf0, v[kb][nd], o[0][nd]);
        o[1][nd] = MFMA_BF16(pf1, v[kb][nd], o[1][nd]);
      }
      lsum[0] = MFMA_BF16(pf0, vones, lsum[0]);
      lsum[1] = MFMA_BF16(pf1, vones, lsum[1]);
    }
  }

  const int b = bh >> 4, h2 = bh & 15;
#pragma unroll
  for (int a = 0; a < 2; ++a)
#pragma unroll
    for (int r = 0; r < 4; ++r) {
      float inv = 1.0f / lsum[a][r];
      int t = q0 + a * 16 + lk * 4 + r;
#pragma unroll
      for (int nd = 0; nd < 4; ++nd)
        ctx[((size_t)b * T_ + t) * E_ + h2 * D_ + nd * 16 + lr] = f2bf(o[a][nd][r] * inv);
    }
}

// ---------------- launcher ----------------
extern "C" void kernel_launch(void* const* d_in, const int* in_sizes, int n_in,
                              void* d_out, int out_size, void* d_ws, size_t ws_size,
                              hipStream_t stream) {
  const float* x    = (const float*)d_in[0];
  const float* Wq   = (const float*)d_in[1];
  const float* Wk   = (const float*)d_in[2];
  const float* Wv   = (const float*)d_in[3];
  const float* Wout = (const float*)d_in[4];
  const float* bout = (const float*)d_in[5];
  float* out = (float*)d_out;

  const size_t MT = (size_t)B_ * T_;      // 8192
  const size_t XE = MT * E_;              // 8,388,608
  const size_t WE = (size_t)E_ * E_;      // 1,048,576

  size_t need = (XE * 5 + WE * 4) * sizeof(unsigned short);
  if (ws_size < need) return;

  unsigned short* xb  = (unsigned short*)d_ws;
  unsigned short* wqb = xb + XE;
  unsigned short* wkb = wqb + WE;
  unsigned short* wvb = wkb + WE;
  unsigned short* wob = wvb + WE;
  unsigned short* Qb  = wob + WE;
  unsigned short* Kb  = Qb + XE;
  unsigned short* VTb = Kb + XE;
  unsigned short* ctx = VTb + XE;

  cvt_f32_bf16<<<(int)(XE / 8 / 256), 256, 0, stream>>>(x, xb, (int)(XE / 8));
  cvt_w4<<<2048, 256, 0, stream>>>(Wq, Wk, Wv, Wout, wqb);

  gemm_qkv<<<dim3(MT / 128, 24), 256, 0, stream>>>(xb, wqb, wkb, wvb, Qb, Kb, VTb);  // V written transposed

  attn_fused<<<4096, 64, 0, stream>>>(Qb, Kb, VTb, ctx);

  gemm_out<<<dim3(MT / 128, E_ / 128), 256, 0, stream>>>(ctx, wob, out, bout, (int)MT, E_, E_);
}

// Round 13
// 206.150 us; speedup vs baseline: 1.1934x; 1.1934x over previous
//
#include <hip/hip_runtime.h>
#include <hip/hip_bf16.h>
#include <stdint.h>
#include <math.h>

#define B_ 4
#define T_ 2048
#define E_ 1024
#define H_ 16
#define D_ 64

typedef __attribute__((ext_vector_type(8))) short short8;
typedef __attribute__((ext_vector_type(4))) short short4v;
typedef __attribute__((ext_vector_type(4))) float f32x4;

#define MFMA_BF16(a, b, c) __builtin_amdgcn_mfma_f32_16x16x32_bf16((a), (b), (c), 0, 0, 0)

__device__ __forceinline__ unsigned short f2bf(float f) {
  union { float f; unsigned u; } v; v.f = f;
  unsigned r = v.u + 0x7FFFu + ((v.u >> 16) & 1u);  // RNE
  return (unsigned short)(r >> 16);
}

#define GLOAD_LDS16(g, l)                                                        \
  __builtin_amdgcn_global_load_lds((const __attribute__((address_space(1))) void*)(g), \
                                   (__attribute__((address_space(3))) void*)(l), 16, 0, 0)

// ---------------- fp32 -> bf16 convert (vectorized) ----------------
__global__ __launch_bounds__(256) void cvt_f32_bf16(const float* __restrict__ in,
                                                    unsigned short* __restrict__ out,
                                                    int n8) {
  int i = blockIdx.x * blockDim.x + threadIdx.x;
  if (i >= n8) return;
  const float4* p = (const float4*)(in + (size_t)i * 8);
  float4 a = p[0], b = p[1];
  short8 r;
  r[0] = (short)f2bf(a.x); r[1] = (short)f2bf(a.y);
  r[2] = (short)f2bf(a.z); r[3] = (short)f2bf(a.w);
  r[4] = (short)f2bf(b.x); r[5] = (short)f2bf(b.y);
  r[6] = (short)f2bf(b.z); r[7] = (short)f2bf(b.w);
  *(short8*)(out + (size_t)i * 8) = r;
}

// 4 weight matrices in one launch (dest regions contiguous in ws)
__global__ __launch_bounds__(256) void cvt_w4(const float* __restrict__ w0,
                                              const float* __restrict__ w1,
                                              const float* __restrict__ w2,
                                              const float* __restrict__ w3,
                                              unsigned short* __restrict__ out) {
  int i = blockIdx.x * blockDim.x + threadIdx.x;  // one per 8 elems
  int which = i >> 17;                            // WE/8 = 2^17
  int off = i & 131071;
  const float* src = (which == 0) ? w0 : (which == 1) ? w1 : (which == 2) ? w2 : w3;
  const float4* p = (const float4*)(src + (size_t)off * 8);
  float4 a = p[0], b = p[1];
  short8 r;
  r[0] = (short)f2bf(a.x); r[1] = (short)f2bf(a.y);
  r[2] = (short)f2bf(a.z); r[3] = (short)f2bf(a.w);
  r[4] = (short)f2bf(b.x); r[5] = (short)f2bf(b.y);
  r[6] = (short)f2bf(b.z); r[7] = (short)f2bf(b.w);
  *(short8*)(out + ((size_t)which << 20) + (size_t)off * 8) = r;
}

// ---------------- fused QKV GEMM: C = x * W^T for W in {Wq,Wk,Wv} -------------
// sel 0/1 (Q,K): bf16 [B*H][T][D]. sel 2 (V): bf16 TRANSPOSED [B*H][D][T] via
// packed 8B stores (4 consecutive t at fixed d).
__global__ __launch_bounds__(256) void gemm_qkv(const unsigned short* __restrict__ A,
                                                const unsigned short* __restrict__ Wq,
                                                const unsigned short* __restrict__ Wk,
                                                const unsigned short* __restrict__ Wv,
                                                unsigned short* __restrict__ Qo,
                                                unsigned short* __restrict__ Ko,
                                                unsigned short* __restrict__ Vo) {
  __shared__ __align__(16) unsigned short Ab[128 * 64];
  __shared__ __align__(16) unsigned short Bb[128 * 64];
  const int K = E_;
  const int tid = threadIdx.x;
  const int wid = tid >> 6;
  const int lr = tid & 15;
  const int lk = (tid >> 4) & 3;
  const int wr = wid >> 1, wc = wid & 1;
  const int m0 = blockIdx.x * 128;
  const int sel = blockIdx.y >> 3;
  const int n0 = (blockIdx.y & 7) * 128;
  const unsigned short* Bm = (sel == 0) ? Wq : (sel == 1) ? Wk : Wv;
  unsigned short* outp = (sel == 0) ? Qo : (sel == 1) ? Ko : Vo;

  f32x4 acc[4][4] = {};

  for (int k0 = 0; k0 < K; k0 += 64) {
    __syncthreads();
#pragma unroll
    for (int pass = 0; pass < 4; ++pass) {
      int chunk = pass * 256 + tid;
      int row = chunk >> 3, inner = chunk & 7;
      const unsigned short* ga = A + (size_t)(m0 + row) * K + k0 + inner * 8;
      const unsigned short* gb = Bm + (size_t)(n0 + row) * K + k0 + inner * 8;
      unsigned short* la = Ab + (size_t)(pass * 256 + wid * 64) * 8;
      unsigned short* lb = Bb + (size_t)(pass * 256 + wid * 64) * 8;
      GLOAD_LDS16(ga, la);
      GLOAD_LDS16(gb, lb);
    }
    __syncthreads();
#pragma unroll
    for (int kk = 0; kk < 2; ++kk) {
      short8 af[4], bf[4];
#pragma unroll
      for (int mi = 0; mi < 4; ++mi)
        af[mi] = *(const short8*)&Ab[(wr * 64 + mi * 16 + lr) * 64 + kk * 32 + lk * 8];
#pragma unroll
      for (int ni = 0; ni < 4; ++ni)
        bf[ni] = *(const short8*)&Bb[(wc * 64 + ni * 16 + lr) * 64 + kk * 32 + lk * 8];
#pragma unroll
      for (int mi = 0; mi < 4; ++mi)
#pragma unroll
        for (int ni = 0; ni < 4; ++ni)
          acc[mi][ni] = MFMA_BF16(af[mi], bf[ni], acc[mi][ni]);
    }
  }

#pragma unroll
  for (int mi = 0; mi < 4; ++mi)
#pragma unroll
    for (int ni = 0; ni < 4; ++ni) {
      int row0 = m0 + wr * 64 + mi * 16 + lk * 4;
      int col = n0 + wc * 64 + ni * 16 + lr;
      int b = row0 >> 11, t0 = row0 & (T_ - 1), h = col >> 6, d = col & (D_ - 1);
      if (sel == 2) {
        short4v vv;
#pragma unroll
        for (int r = 0; r < 4; ++r) vv[r] = (short)f2bf(acc[mi][ni][r]);
        *(short4v*)&outp[(((size_t)(b * H_ + h)) * D_ + d) * T_ + t0] = vv;  // [BH][D][T]
      } else {
#pragma unroll
        for (int r = 0; r < 4; ++r)
          outp[(((size_t)(b * H_ + h)) * T_ + t0 + r) * D_ + d] = f2bf(acc[mi][ni][r]);
      }
    }
}

// ---------------- out-proj GEMM: fp32 out + bias ----------------
__global__ __launch_bounds__(256) void gemm_out(const unsigned short* __restrict__ A,
                                                const unsigned short* __restrict__ Bm,
                                                float* __restrict__ outp,
                                                const float* __restrict__ bias,
                                                int M, int N, int K) {
  __shared__ __align__(16) unsigned short Ab[128 * 64];
  __shared__ __align__(16) unsigned short Bb[128 * 64];
  const int tid = threadIdx.x;
  const int wid = tid >> 6;
  const int lr = tid & 15;
  const int lk = (tid >> 4) & 3;
  const int wr = wid >> 1, wc = wid & 1;
  const int m0 = blockIdx.x * 128, n0 = blockIdx.y * 128;

  f32x4 acc[4][4] = {};

  for (int k0 = 0; k0 < K; k0 += 64) {
    __syncthreads();
#pragma unroll
    for (int pass = 0; pass < 4; ++pass) {
      int chunk = pass * 256 + tid;
      int row = chunk >> 3, inner = chunk & 7;
      const unsigned short* ga = A + (size_t)(m0 + row) * K + k0 + inner * 8;
      const unsigned short* gb = Bm + (size_t)(n0 + row) * K + k0 + inner * 8;
      unsigned short* la = Ab + (size_t)(pass * 256 + wid * 64) * 8;
      unsigned short* lb = Bb + (size_t)(pass * 256 + wid * 64) * 8;
      GLOAD_LDS16(ga, la);
      GLOAD_LDS16(gb, lb);
    }
    __syncthreads();
#pragma unroll
    for (int kk = 0; kk < 2; ++kk) {
      short8 af[4], bf[4];
#pragma unroll
      for (int mi = 0; mi < 4; ++mi)
        af[mi] = *(const short8*)&Ab[(wr * 64 + mi * 16 + lr) * 64 + kk * 32 + lk * 8];
#pragma unroll
      for (int ni = 0; ni < 4; ++ni)
        bf[ni] = *(const short8*)&Bb[(wc * 64 + ni * 16 + lr) * 64 + kk * 32 + lk * 8];
#pragma unroll
      for (int mi = 0; mi < 4; ++mi)
#pragma unroll
        for (int ni = 0; ni < 4; ++ni)
          acc[mi][ni] = MFMA_BF16(af[mi], bf[ni], acc[mi][ni]);
    }
  }

#pragma unroll
  for (int mi = 0; mi < 4; ++mi)
#pragma unroll
    for (int ni = 0; ni < 4; ++ni)
#pragma unroll
      for (int r = 0; r < 4; ++r) {
        int row = m0 + wr * 64 + mi * 16 + lk * 4 + r;
        int col = n0 + wc * 64 + ni * 16 + lr;
        outp[(size_t)row * N + col] = acc[mi][ni][r] + bias[col];
      }
}

// ---------------- fused causal flash attention (r11 body + pair balance) -----
// 1024 blocks x 64 thr. Block = pair of 64-row groups (31-g, g) of one head:
// EXACTLY 33 tiles per block -> all 4 blocks/CU finish together (no drain,
// no solo tail). Per group: r11's lagged-PV pipeline (chunks A,B share K/V;
// PV(i-1) overlaps QK(i); double-buffered P + K/V regs; no fences).
__device__ __forceinline__ void attn_group(int q0,
                                           const unsigned short* __restrict__ Qh,
                                           const unsigned short* __restrict__ Kh,
                                           const unsigned short* __restrict__ Vh,
                                           unsigned short* __restrict__ ctx,
                                           int b, int h2, int lane, int lr, int lk,
                                           char* bufA, char* bufB) {
  const float SC = 0.125f * 1.44269504089f;  // 1/sqrt(D) * log2(e)

  short8 vones;
#pragma unroll
  for (int j = 0; j < 8; ++j) vones[j] = (short)0x3F80;  // bf16 1.0

  short8 qfA[2][2], qfB[2][2];
#pragma unroll
  for (int a = 0; a < 2; ++a)
#pragma unroll
    for (int kb = 0; kb < 2; ++kb) {
      qfA[a][kb] = *(const short8*)&Qh[(size_t)(q0 + a * 16 + lr) * D_ + kb * 32 + lk * 8];
      qfB[a][kb] = *(const short8*)&Qh[(size_t)(q0 + 32 + a * 16 + lr) * D_ + kb * 32 + lk * 8];
    }

  f32x4 oA[2][4] = {}, oB[2][4] = {};
  f32x4 lsA[2] = {}, lsB[2] = {};
  float mA[2] = {-1e30f, -1e30f}, mB[2] = {-1e30f, -1e30f};

  const int nt = (q0 >> 6) + 1;

  auto loadK = [&](short8(&kf)[2][4], int t) {
    const unsigned short* Kt = Kh + (size_t)t * 64 * D_;
#pragma unroll
    for (int kb = 0; kb < 2; ++kb)
#pragma unroll
      for (int n = 0; n < 4; ++n)
        kf[kb][n] = *(const short8*)&Kt[(size_t)(n * 16 + lr) * D_ + kb * 32 + lk * 8];
  };
  auto loadV = [&](short8(&v)[2][4], int t) {
    const unsigned short* Vtt = Vh + (size_t)t * 64;
#pragma unroll
    for (int kb = 0; kb < 2; ++kb)
#pragma unroll
      for (int nd = 0; nd < 4; ++nd)
        v[kb][nd] = *(const short8*)&Vtt[(size_t)(nd * 16 + lr) * T_ + kb * 32 + lk * 8];
  };
  auto rowmax = [&](f32x4(&st)[2][4], float(&pm)[2]) {
#pragma unroll
    for (int a = 0; a < 2; ++a) {
      float m0 = fmaxf(fmaxf(st[a][0][0], st[a][1][0]), fmaxf(st[a][2][0], st[a][3][0]));
      float m1 = fmaxf(fmaxf(st[a][0][1], st[a][1][1]), fmaxf(st[a][2][1], st[a][3][1]));
      float m2 = fmaxf(fmaxf(st[a][0][2], st[a][1][2]), fmaxf(st[a][2][2], st[a][3][2]));
      float m3 = fmaxf(fmaxf(st[a][0][3], st[a][1][3]), fmaxf(st[a][2][3], st[a][3][3]));
      float mx = fmaxf(fmaxf(m0, m1), fmaxf(m2, m3));
      mx = fmaxf(mx, __shfl_xor(mx, 16));
      mx = fmaxf(mx, __shfl_xor(mx, 32));
      pm[a] = mx * SC;
    }
  };
  auto rescale1 = [&](float(&pm)[2], float(&mrun)[2], f32x4(&ls)[2], f32x4(&o)[2][4]) {
#pragma unroll
    for (int a = 0; a < 2; ++a) {
      float mnew = fmaxf(mrun[a], pm[a]);
      float sc = exp2f(mrun[a] - mnew);
      mrun[a] = mnew;
#pragma unroll
      for (int r = 0; r < 4; ++r) {
        float sco = __shfl(sc, (lane & 48) | (lk * 4 + r));
        ls[a][r] *= sco;
#pragma unroll
        for (int nd = 0; nd < 4; ++nd) o[a][nd][r] *= sco;
      }
    }
  };
  auto pack = [&](f32x4(&st)[2][4], float(&mrun)[2], char* buf, int rb) {
#pragma unroll
    for (int a = 0; a < 2; ++a)
#pragma unroll
      for (int n = 0; n < 4; ++n) {
        float2 p01, p23;
        p01.x = exp2f(fmaf(st[a][n][0], SC, -mrun[a]));
        p01.y = exp2f(fmaf(st[a][n][1], SC, -mrun[a]));
        p23.x = exp2f(fmaf(st[a][n][2], SC, -mrun[a]));
        p23.y = exp2f(fmaf(st[a][n][3], SC, -mrun[a]));
        __hip_bfloat162 b01 = __float22bfloat162_rn(p01);
        __hip_bfloat162 b23 = __float22bfloat162_rn(p23);
        uint2 w;
        w.x = *(unsigned*)&b01;
        w.y = *(unsigned*)&b23;
        *(uint2*)(buf + (rb + a * 16 + lr) * 144 + n * 32 + lk * 8) = w;
      }
  };
  auto pv = [&](char* buf, short8(&v)[2][4]) {
#pragma unroll
    for (int kb = 0; kb < 2; ++kb) {
      short8 pfA0 = *(const short8*)(buf + (0 + lr) * 144 + kb * 64 + lk * 16);
      short8 pfA1 = *(const short8*)(buf + (16 + lr) * 144 + kb * 64 + lk * 16);
      short8 pfB0 = *(const short8*)(buf + (32 + lr) * 144 + kb * 64 + lk * 16);
      short8 pfB1 = *(const short8*)(buf + (48 + lr) * 144 + kb * 64 + lk * 16);
#pragma unroll
      for (int nd = 0; nd < 4; ++nd) {
        oA[0][nd] = MFMA_BF16(pfA0, v[kb][nd], oA[0][nd]);
        oA[1][nd] = MFMA_BF16(pfA1, v[kb][nd], oA[1][nd]);
        oB[0][nd] = MFMA_BF16(pfB0, v[kb][nd], oB[0][nd]);
        oB[1][nd] = MFMA_BF16(pfB1, v[kb][nd], oB[1][nd]);
      }
      lsA[0] = MFMA_BF16(pfA0, vones, lsA[0]);
      lsA[1] = MFMA_BF16(pfA1, vones, lsA[1]);
      lsB[0] = MFMA_BF16(pfB0, vones, lsB[0]);
      lsB[1] = MFMA_BF16(pfB1, vones, lsB[1]);
    }
  };

  // per-tile body: QK(i) + rowmax + [PV(i-1)] + rescale + pack(i)
  auto tile = [&](int i, bool diag, bool doPV,
                  short8(&kfc)[2][4], short8(&kfn)[2][4],
                  short8(&vp)[2][4], short8(&vc)[2][4],
                  char* bufp, char* bufc, int tnext) {
    loadK(kfn, tnext);
    loadV(vc, i);
    f32x4 stA[2][4] = {}, stB[2][4] = {};
#pragma unroll
    for (int kb = 0; kb < 2; ++kb)
#pragma unroll
      for (int a = 0; a < 2; ++a)
#pragma unroll
        for (int n = 0; n < 4; ++n) {
          stA[a][n] = MFMA_BF16(kfc[kb][n], qfA[a][kb], stA[a][n]);
          stB[a][n] = MFMA_BF16(kfc[kb][n], qfB[a][kb], stB[a][n]);
        }
    if (diag) {
#pragma unroll
      for (int a = 0; a < 2; ++a)
#pragma unroll
        for (int n = 0; n < 4; ++n)
#pragma unroll
          for (int r = 0; r < 4; ++r) {
            if (n * 16 + lk * 4 + r > 0 + a * 16 + lr) stA[a][n][r] = -3e38f;
            if (n * 16 + lk * 4 + r > 32 + a * 16 + lr) stB[a][n][r] = -3e38f;
          }
    }
    float pmA[2], pmB[2];
    rowmax(stA, pmA);
    rowmax(stB, pmB);
    float need = fmaxf(fmaxf(pmA[0] - mA[0], pmA[1] - mA[1]),
                       fmaxf(pmB[0] - mB[0], pmB[1] - mB[1]));
    if (doPV) pv(bufp, vp);  // absorbs tile i-1 at OLD scale (before rescale)
    if (__any(need > 8.f)) {
      rescale1(pmA, mA, lsA, oA);
      rescale1(pmB, mB, lsB, oB);
    }
    pack(stA, mA, bufc, 0);
    pack(stB, mB, bufc, 32);
  };

  short8 kf0[2][4], kf1[2][4], v0[2][4], v1[2][4];

  // prologue: tile 0 (no PV), K(1) prefetched
  loadK(kf0, 0);
  tile(0, nt == 1, false, kf0, kf1, v1, v0, bufB, bufA, (1 < nt) ? 1 : 0);

  int i = 1;
  while (i < nt) {
    tile(i, i == nt - 1, true, kf1, kf0, v0, v1, bufA, bufB, (i + 1 < nt) ? i + 1 : i);
    if (++i >= nt) break;
    tile(i, i == nt - 1, true, kf0, kf1, v1, v0, bufB, bufA, (i + 1 < nt) ? i + 1 : i);
    ++i;
  }
  // epilogue: PV of last tile
  if ((nt - 1) & 1) pv(bufB, v1);
  else              pv(bufA, v0);

#pragma unroll
  for (int a = 0; a < 2; ++a)
#pragma unroll
    for (int r = 0; r < 4; ++r) {
      float invA = 1.0f / lsA[a][r];
      float invB = 1.0f / lsB[a][r];
      int tA = q0 + a * 16 + lk * 4 + r;
      int tB = tA + 32;
#pragma unroll
      for (int nd = 0; nd < 4; ++nd) {
        ctx[((size_t)b * T_ + tA) * E_ + h2 * D_ + nd * 16 + lr] = f2bf(oA[a][nd][r] * invA);
        ctx[((size_t)b * T_ + tB) * E_ + h2 * D_ + nd * 16 + lr] = f2bf(oB[a][nd][r] * invB);
      }
    }
}

__global__ __launch_bounds__(64) void attn_fused(const unsigned short* __restrict__ Q,
                                                 const unsigned short* __restrict__ K,
                                                 const unsigned short* __restrict__ VT,
                                                 unsigned short* __restrict__ ctx) {
  __shared__ __align__(16) unsigned short Pl[2][64 * 72];  // 2 bufs x 64 rows x 144B
  const int lane = threadIdx.x & 63;
  const int lr = lane & 15;
  const int lk = lane >> 4;

  // 1024 blocks = 8 XCD x 8 heads x 16 pairs; pair (31-g, g) => 33 tiles each.
  const int bid = blockIdx.x;
  const int xcd = bid & 7;
  const int p = bid >> 3;        // 0..127 per XCD
  const int bh = xcd * 8 + (p & 7);
  const int g = p >> 3;          // 0..15

  const unsigned short* Qh = Q + (size_t)bh * T_ * D_;
  const unsigned short* Kh = K + (size_t)bh * T_ * D_;
  const unsigned short* Vh = VT + (size_t)bh * T_ * D_;  // [D][T]
  const int b = bh >> 4, h2 = bh & 15;
  char* bufA = (char*)&Pl[0][0];
  char* bufB = (char*)&Pl[1][0];

  attn_group((31 - g) * 64, Qh, Kh, Vh, ctx, b, h2, lane, lr, lk, bufA, bufB);
  attn_group(g * 64,        Qh, Kh, Vh, ctx, b, h2, lane, lr, lk, bufA, bufB);
}

// ---------------- launcher ----------------
extern "C" void kernel_launch(void* const* d_in, const int* in_sizes, int n_in,
                              void* d_out, int out_size, void* d_ws, size_t ws_size,
                              hipStream_t stream) {
  const float* x    = (const float*)d_in[0];
  const float* Wq   = (const float*)d_in[1];
  const float* Wk   = (const float*)d_in[2];
  const float* Wv   = (const float*)d_in[3];
  const float* Wout = (const float*)d_in[4];
  const float* bout = (const float*)d_in[5];
  float* out = (float*)d_out;

  const size_t MT = (size_t)B_ * T_;      // 8192
  const size_t XE = MT * E_;              // 8,388,608
  const size_t WE = (size_t)E_ * E_;      // 1,048,576

  size_t need = (XE * 5 + WE * 4) * sizeof(unsigned short);
  if (ws_size < need) return;

  unsigned short* xb  = (unsigned short*)d_ws;
  unsigned short* wqb = xb + XE;
  unsigned short* wkb = wqb + WE;
  unsigned short* wvb = wkb + WE;
  unsigned short* wob = wvb + WE;
  unsigned short* Qb  = wob + WE;
  unsigned short* Kb  = Qb + XE;
  unsigned short* VTb = Kb + XE;
  unsigned short* ctx = VTb + XE;

  cvt_f32_bf16<<<(int)(XE / 8 / 256), 256, 0, stream>>>(x, xb, (int)(XE / 8));
  cvt_w4<<<2048, 256, 0, stream>>>(Wq, Wk, Wv, Wout, wqb);

  gemm_qkv<<<dim3(MT / 128, 24), 256, 0, stream>>>(xb, wqb, wkb, wvb, Qb, Kb, VTb);  // V written transposed

  attn_fused<<<1024, 64, 0, stream>>>(Qb, Kb, VTb, ctx);

  gemm_out<<<dim3(MT / 128, E_ / 128), 256, 0, stream>>>(ctx, wob, out, bout, (int)MT, E_, E_);
}